// Round 12
// baseline (299.616 us; speedup 1.0000x reference)
//
#include <hip/hip_runtime.h>
#include <hip/hip_bf16.h>
#include <stdint.h>

#define HGT   24
#define WID   24
#define NHEAD 12
#define EMB   768
#define HD    64
#define NGRID 576
#define NTOK  577
#define NPAD  640              // padded token dim (10 tiles of 64)
#define BATCH 32
#define MROWS (BATCH * NTOK)   // 18464
#define NKT   10
#define NIT   5                // 5 iterations x 128 keys
#define NQT   5                // 5 q-tiles of 128
#define QKVC  (3 * EMB)        // 2304

typedef __attribute__((ext_vector_type(8))) short bf16x8;
typedef __attribute__((ext_vector_type(4))) float f32x4;

__device__ __forceinline__ short f2bf(float f) {
    union { float f; unsigned u; } c; c.f = f;
    unsigned r = (c.u + 0x7FFFu + ((c.u >> 16) & 1u)) >> 16;
    return (short)(r & 0xFFFFu);
}
__device__ __forceinline__ float b2f(short s) {
    union { unsigned u; float f; } c; c.u = ((unsigned)(unsigned short)s) << 16;
    return c.f;
}
// packed f32x2 -> bf16x2 (compiler emits v_cvt_pk_bf16_f32)
__device__ __forceinline__ unsigned pk2bf(float a, float b) {
    __hip_bfloat162 h = __float22bfloat162_rn(make_float2(a, b));
    union { __hip_bfloat162 h; unsigned u; } c; c.h = h;
    return c.u;
}
__device__ __forceinline__ float fexp2(float x) {
#if __has_builtin(__builtin_amdgcn_exp2f)
    return __builtin_amdgcn_exp2f(x);
#else
    return __expf(x * 0.69314718f);
#endif
}

// async global->LDS, 16B per lane; LDS dest = wave-uniform base + lane*16
__device__ __forceinline__ void gload16(void* lds, const void* g) {
    __builtin_amdgcn_global_load_lds(
        (const __attribute__((address_space(1))) void*)g,
        (__attribute__((address_space(3))) void*)lds, 16, 0, 0);
}

__device__ __forceinline__ void wait_vm0_barrier() {
    asm volatile("s_waitcnt vmcnt(0)" ::: "memory");
    __builtin_amdgcn_s_barrier();
}

// bijective XCD-chunk swizzle (m204)
__device__ __forceinline__ int xcd_swizzle(int orig, int nwg) {
    int q = nwg >> 3, r = nwg & 7;
    int xcd = orig & 7, idx = orig >> 3;
    return (xcd < r) ? xcd * (q + 1) + idx : r * (q + 1) + (xcd - r) * q + idx;
}

// ---------------------------------------------------------------- cast f32->bf16
__global__ void cast_f32_bf16(const float* __restrict__ src, short* __restrict__ dst, int n) {
    int i = (blockIdx.x * blockDim.x + threadIdx.x) * 4;
    int stride = gridDim.x * blockDim.x * 4;
    for (int j = i; j < n; j += stride) {
        float4 v = *(const float4*)(src + j);
        uint2 o;
        o.x = pk2bf(v.x, v.y);
        o.y = pk2bf(v.z, v.w);
        *(uint2*)(dst + j) = o;
    }
}

// ---------------------------------------------------------------- bias table bf16 [H][q 640][k 640]
// PRE-SCALED by log2(e) (softmax runs in log2 domain).
__global__ void bias_expand(const float* __restrict__ rel, short* __restrict__ be) {
    const float L2E = 1.44269504f;
    int q = blockIdx.x;     // query 0..639
    int k = threadIdx.x;    // key   0..639
    float v[NHEAD];
    if (k >= NTOK) {
#pragma unroll
        for (int h = 0; h < NHEAD; h++) v[h] = -1e30f;
    } else if (q == 0 || q >= NTOK || k == 0) {
#pragma unroll
        for (int h = 0; h < NHEAD; h++) v[h] = 0.f;
    } else {
        int i = q - 1, j = k - 1;
        int idx = ((i / WID) - (j / WID) + HGT - 1) * (2 * WID - 1)
                + ((i % WID) - (j % WID) + WID - 1);
        const float* rp = rel + (size_t)idx * NHEAD;
#pragma unroll
        for (int h = 0; h < NHEAD; h++) v[h] = rp[h];
    }
#pragma unroll
    for (int h = 0; h < NHEAD; h++)
        be[((size_t)h * NPAD + q) * NPAD + k] = f2bf(v[h] * L2E);
}

// ---------------------------------------------------------------- GEMM  C = A @ B^T (+bias)
// 256x256 tile, BK=32, 8 waves (512 thr), 4 LDS buffers, uniform 3-step
// prefetch distance, counted vmcnt(8) (never 0 until tail), ONE barrier/step.
// Transposed accumulation (mfma(B,A)) -> wide C stores.
// MODE 0: NC=2304, bf16 out -> qnat[m][2304]; V third (cols>=1536) scatters
//         TRANSPOSED into vout[b][h][d][key(640)] (fuses transpose_v).
// MODE 1: NC=768, f32 out + b0.
template <int MODE>
__global__ __launch_bounds__(512) void gemm_bt(
    const short* __restrict__ A, const short* __restrict__ Bw,
    const float* __restrict__ b0, const float* __restrict__ b1, const float* __restrict__ b2,
    void* __restrict__ Outp, short* __restrict__ vout, int M)
{
    constexpr int NC  = (MODE == 0) ? QKVC : EMB;
    constexpr int NBX = NC / 256;     // 9 or 3
    constexpr int K   = EMB;          // 768
    constexpr int NST = K / 32;       // 24 K-steps

    __shared__ __align__(16) short Asl[4][256][32];   // 64 KB
    __shared__ __align__(16) short Bsl[4][256][32];   // 64 KB

    const int t    = threadIdx.x;
    const int lane = t & 63;
    const int w    = t >> 6;          // 0..7
    const int wm   = w >> 2;          // 0..1  (M half)
    const int wn   = w & 3;           // 0..3  (N quarter)
    const int lg   = lane >> 4;
    const int li   = lane & 15;

    const int nwg  = NBX * ((MROWS + 255) / 256);     // 9*73 or 3*73
    const int wgid = xcd_swizzle(blockIdx.x, nwg);
    const int tm   = (wgid / NBX) * 256;
    const int tn   = (wgid % NBX) * 256;

    const int drow = lane >> 2;                        // 0..15
    const int lc   = (lane & 3) ^ ((lane >> 3) & 3);   // source logical chunk
    const int xsw  = (li >> 1) & 3;                    // read-side chunk XOR

    const short* agp[2];
    const short* bgp[2];
#pragma unroll
    for (int gi = 0; gi < 2; gi++) {
        int rm = tm + gi * 128 + w * 16 + drow; if (rm >= M) rm = M - 1;
        agp[gi] = A  + (size_t)rm * K + lc * 8;
        bgp[gi] = Bw + (size_t)(tn + gi * 128 + w * 16 + drow) * K + lc * 8;
    }

    f32x4 acc[8][4];
#pragma unroll
    for (int i = 0; i < 8; i++)
#pragma unroll
        for (int j = 0; j < 4; j++) acc[i][j] = (f32x4){0.f, 0.f, 0.f, 0.f};

    // prologue: stage steps 0..2 (4 gloads/wave each)
#pragma unroll
    for (int ss = 0; ss < 3; ss++) {
        gload16(&Asl[ss][0 * 128 + w * 16][0], agp[0] + ss * 32);
        gload16(&Asl[ss][1 * 128 + w * 16][0], agp[1] + ss * 32);
        gload16(&Bsl[ss][0 * 128 + w * 16][0], bgp[0] + ss * 32);
        gload16(&Bsl[ss][1 * 128 + w * 16][0], bgp[1] + ss * 32);
    }

    for (int s = 0; s < NST; s++) {
        if (s < NST - 2)       asm volatile("s_waitcnt vmcnt(8)" ::: "memory");
        else if (s == NST - 2) asm volatile("s_waitcnt vmcnt(4)" ::: "memory");
        else                   asm volatile("s_waitcnt vmcnt(0)" ::: "memory");
        __builtin_amdgcn_s_barrier();

        const int cb = s & 3;
        bf16x8 af[8], bfv[4];
#pragma unroll
        for (int mi = 0; mi < 8; mi++)
            af[mi] = *(const bf16x8*)&Asl[cb][wm * 128 + mi * 16 + li][(lg ^ xsw) * 8];
#pragma unroll
        for (int nj = 0; nj < 4; nj++)
            bfv[nj] = *(const bf16x8*)&Bsl[cb][wn * 64 + nj * 16 + li][(lg ^ xsw) * 8];

        if (s + 3 < NST) {
            const int tb = (s + 3) & 3;
            const int ko = (s + 3) * 32;
            gload16(&Asl[tb][0 * 128 + w * 16][0], agp[0] + ko);
            gload16(&Asl[tb][1 * 128 + w * 16][0], agp[1] + ko);
            gload16(&Bsl[tb][0 * 128 + w * 16][0], bgp[0] + ko);
            gload16(&Bsl[tb][1 * 128 + w * 16][0], bgp[1] + ko);
        }

        __builtin_amdgcn_s_setprio(1);
#pragma unroll
        for (int mi = 0; mi < 8; mi++)
#pragma unroll
            for (int nj = 0; nj < 4; nj++)
                acc[mi][nj] = __builtin_amdgcn_mfma_f32_16x16x32_bf16(
                    bfv[nj], af[mi], acc[mi][nj], 0, 0, 0);   // transposed: C^T frags
        __builtin_amdgcn_s_setprio(0);
    }

    // epilogue: lane holds C[row = wm*128+mi*16+li][cols = ccb..ccb+3]
    if (MODE == 0 && tn >= 2 * EMB) {
        // V third: scatter transposed into vout[b][h][d][key]
#pragma unroll
        for (int nj = 0; nj < 4; nj++) {
            const int ccb = tn + wn * 64 + nj * 16 + lg * 4;
            const int e   = ccb - 2 * EMB;
            const int hh  = e >> 6, db = e & 63;
            const float4 bias4 = *(const float4*)&b2[e];
#pragma unroll
            for (int mi = 0; mi < 8; mi++) {
                int m = tm + wm * 128 + mi * 16 + li;
                if (m >= M) continue;
                int bi = m / NTOK;
                int n  = m - bi * NTOK;
                short* vr = vout + (((size_t)bi * NHEAD + hh) * HD + db) * NPAD + n;
                vr[0 * NPAD] = f2bf(acc[mi][nj][0] + bias4.x);
                vr[1 * NPAD] = f2bf(acc[mi][nj][1] + bias4.y);
                vr[2 * NPAD] = f2bf(acc[mi][nj][2] + bias4.z);
                vr[3 * NPAD] = f2bf(acc[mi][nj][3] + bias4.w);
            }
        }
    } else {
#pragma unroll
        for (int nj = 0; nj < 4; nj++) {
            const int ccb = tn + wn * 64 + nj * 16 + lg * 4;
            float4 bias4;
            if constexpr (MODE == 0) {
                int which = (ccb >= EMB) ? 1 : 0;   // V handled above
                const float* bb = (which == 0) ? b0 : b1;
                bias4 = *(const float4*)&bb[ccb - which * EMB];
            } else {
                bias4 = *(const float4*)&b0[ccb];
            }
#pragma unroll
            for (int mi = 0; mi < 8; mi++) {
                int m = tm + wm * 128 + mi * 16 + li;
                if (m >= M) continue;
                if constexpr (MODE == 0) {
                    uint2 o;
                    o.x = pk2bf(acc[mi][nj][0] + bias4.x, acc[mi][nj][1] + bias4.y);
                    o.y = pk2bf(acc[mi][nj][2] + bias4.z, acc[mi][nj][3] + bias4.w);
                    *(uint2*)&((short*)Outp)[(size_t)m * NC + ccb] = o;
                } else {
                    float4 o;
                    o.x = acc[mi][nj][0] + bias4.x;
                    o.y = acc[mi][nj][1] + bias4.y;
                    o.z = acc[mi][nj][2] + bias4.z;
                    o.w = acc[mi][nj][3] + bias4.w;
                    *(float4*)&((float*)Outp)[(size_t)m * NC + ccb] = o;
                }
            }
        }
    }
}

// ---------------------------------------------------------------- flash attention (swapped QK^T, log2 softmax)
// 256 threads = 4 waves x 32 queries (2 q-groups of 16) = 128 q per block.
// LDS-traffic-minimized: K frags feed 2 MFMAs; V frags hoisted to regs and
// reused across q-groups; P frags hoisted out of dd loop.
__global__ __launch_bounds__(256) void attn_kernel(
    const short* __restrict__ qnat, const short* __restrict__ vt,
    const short* __restrict__ biasx, short* __restrict__ aout)
{
    __shared__ __align__(16) short Ksl[2][2][64][64];   // [buf][subtile][key][d]  32 KB
    __shared__ __align__(16) short Vsl[2][2][64][64];   // [buf][subtile][d][key]  32 KB
    __shared__ __align__(16) short Psl[4][16][64];      // [wave][q(li)][key]       8 KB

    const int wg = (blockIdx.x & 7) * (BATCH * NHEAD * NQT / 8) + (blockIdx.x >> 3);
    const int qt = wg % NQT;
    const int rest = wg / NQT;        // 0..383
    const int b  = rest & 31;
    const int h  = rest >> 5;

    const int t    = threadIdx.x;
    const int lane = t & 63;
    const int w    = t >> 6;          // 0..3
    const int lg   = lane >> 4;
    const int li   = lane & 15;
    const int xh   = li & 7;
    const int qbase = qt * 128;
    const int myq[2] = { qbase + w * 32 + li, qbase + w * 32 + 16 + li };

    const float SCL = 0.18033688f;    // 0.125 * log2(e)

    const short* qp  = qnat + (size_t)b * NTOK * QKVC + h * HD;          // + n*QKVC
    const short* kp  = qp + EMB;
    const short* vtp = vt + ((size_t)b * NHEAD + h) * (size_t)HD * NPAD;
    const short* browq[2] = { biasx + ((size_t)h * NPAD + myq[0]) * NPAD,
                              biasx + ((size_t)h * NPAD + myq[1]) * NPAD };

    bf16x8 qf[2][2];   // [q2][half]: B-fragment of Q[myq[q2]][k]
#pragma unroll
    for (int q2 = 0; q2 < 2; q2++) {
        int qrow = myq[q2] < NTOK ? myq[q2] : NTOK - 1;
        qf[q2][0] = *(const bf16x8*)(qp + (size_t)qrow * QKVC + lg * 8);
        qf[q2][1] = *(const bf16x8*)(qp + (size_t)qrow * QKVC + 32 + lg * 8);
    }

    float mrun[2] = { -1e30f, -1e30f }, lrun[2] = { 0.f, 0.f };
    f32x4 oacc[2][4];
#pragma unroll
    for (int q2 = 0; q2 < 2; q2++)
#pragma unroll
        for (int d = 0; d < 4; d++) oacc[q2][d] = (f32x4){0.f, 0.f, 0.f, 0.f};

    // staging: 256 thr -> one gload covers 32 rows; wave w rows w*8..+7 per issue
    const int srow = w * 8 + (lane >> 3);             // 0..31
    const int cofs = ((lane & 7) ^ (lane >> 3)) * 8;

    // prologue: stage iteration 0 (both subtiles, p=0,1)
#pragma unroll
    for (int st = 0; st < 2; st++)
#pragma unroll
        for (int p = 0; p < 2; p++) {
            int key = st * 64 + p * 32 + srow; if (key >= NTOK) key = NTOK - 1;
            gload16(&Ksl[0][st][p * 32 + w * 8][0], kp + (size_t)key * QKVC + cofs);
            gload16(&Vsl[0][st][p * 32 + w * 8][0],
                    vtp + (size_t)(p * 32 + srow) * NPAD + st * 64 + cofs);
        }
    short4 bcur[2][2][4];   // [q2][st][j]
#pragma unroll
    for (int q2 = 0; q2 < 2; q2++)
#pragma unroll
        for (int st = 0; st < 2; st++)
#pragma unroll
            for (int j = 0; j < 4; j++)
                bcur[q2][st][j] = *(const short4*)&browq[q2][st * 64 + j * 16 + lg * 4];
    wait_vm0_barrier();

    for (int it = 0; it < NIT; it++) {
        const int cb = it & 1, nb = cb ^ 1;

        // prefetch next iteration's K/V (LDS)
        if (it + 1 < NIT) {
#pragma unroll
            for (int st = 0; st < 2; st++)
#pragma unroll
                for (int p = 0; p < 2; p++) {
                    int key = (it + 1) * 128 + st * 64 + p * 32 + srow;
                    if (key >= NTOK) key = NTOK - 1;
                    gload16(&Ksl[nb][st][p * 32 + w * 8][0], kp + (size_t)key * QKVC + cofs);
                    gload16(&Vsl[nb][st][p * 32 + w * 8][0],
                            vtp + (size_t)(p * 32 + srow) * NPAD + (it + 1) * 128 + st * 64 + cofs);
                }
        }

        // S^T = K @ Q^T (log2 domain) + bias^T; each K fragment feeds both q-groups
        float pvv[2][2][4][4];   // [st][q2][j][r]
        __builtin_amdgcn_s_setprio(1);
#pragma unroll
        for (int st = 0; st < 2; st++) {
#pragma unroll
            for (int j = 0; j < 4; j++) {
                bf16x8 ak0 = *(const bf16x8*)&Ksl[cb][st][j * 16 + li][(lg ^ xh) * 8];
                bf16x8 ak1 = *(const bf16x8*)&Ksl[cb][st][j * 16 + li][((4 + lg) ^ xh) * 8];
#pragma unroll
                for (int q2 = 0; q2 < 2; q2++) {
                    f32x4 s = (f32x4){0.f, 0.f, 0.f, 0.f};
                    s = __builtin_amdgcn_mfma_f32_16x16x32_bf16(ak0, qf[q2][0], s, 0, 0, 0);
                    s = __builtin_amdgcn_mfma_f32_16x16x32_bf16(ak1, qf[q2][1], s, 0, 0, 0);
                    pvv[st][q2][j][0] = fmaf(s[0], SCL, b2f(bcur[q2][st][j].x));
                    pvv[st][q2][j][1] = fmaf(s[1], SCL, b2f(bcur[q2][st][j].y));
                    pvv[st][q2][j][2] = fmaf(s[2], SCL, b2f(bcur[q2][st][j].z));
                    pvv[st][q2][j][3] = fmaf(s[3], SCL, b2f(bcur[q2][st][j].w));
                }
            }
        }
        __builtin_amdgcn_s_setprio(0);

        // online softmax over 128 keys (log2 domain), defer-max (T13), per q-group
        float mt[2];
#pragma unroll
        for (int q2 = 0; q2 < 2; q2++) {
            float m = pvv[0][q2][0][0];
#pragma unroll
            for (int st = 0; st < 2; st++)
#pragma unroll
                for (int j = 0; j < 4; j++)
#pragma unroll
                    for (int r = 0; r < 4; r++) m = fmaxf(m, pvv[st][q2][j][r]);
            m = fmaxf(m, __shfl_xor(m, 16, 64));
            m = fmaxf(m, __shfl_xor(m, 32, 64));
            mt[q2] = m;
        }
        bool need = (mt[0] > mrun[0] + 8.0f) || (mt[1] > mrun[1] + 8.0f);
        if (__any(need)) {
#pragma unroll
            for (int q2 = 0; q2 < 2; q2++) {
                float nm  = fmaxf(mrun[q2], mt[q2]);
                float fac = fexp2(mrun[q2] - nm);
                mrun[q2] = nm;
                lrun[q2] *= fac;
#pragma unroll
                for (int d = 0; d < 4; d++) oacc[q2][d] *= fac;
            }
        }
#pragma unroll
        for (int q2 = 0; q2 < 2; q2++) {
            float rs = 0.f;
#pragma unroll
            for (int st = 0; st < 2; st++)
#pragma unroll
                for (int j = 0; j < 4; j++)
#pragma unroll
                    for (int r = 0; r < 4; r++) {
                        float p = fexp2(pvv[st][q2][j][r] - mrun[q2]);
                        pvv[st][q2][j][r] = p;
                        rs += p;
                    }
            rs += __shfl_xor(rs, 16, 64);
            rs += __shfl_xor(rs, 32, 64);
            lrun[q2] += rs;
        }

        // PV: per subtile, hoist V frags to regs (reused across q-groups),
        // P frags hoisted out of dd loop
#pragma unroll
        for (int st = 0; st < 2; st++) {
            bf16x8 av[4][2];
#pragma unroll
            for (int dd = 0; dd < 4; dd++)
#pragma unroll
                for (int kk = 0; kk < 2; kk++)
                    av[dd][kk] = *(const bf16x8*)&Vsl[cb][st][dd * 16 + li][((kk * 4 + lg) ^ xh) * 8];
#pragma unroll
            for (int q2 = 0; q2 < 2; q2++) {
#pragma unroll
                for (int j = 0; j < 4; j++) {
                    uint2 pw;
                    pw.x = pk2bf(pvv[st][q2][j][0], pvv[st][q2][j][1]);
                    pw.y = pk2bf(pvv[st][q2][j][2], pvv[st][q2][j][3]);
                    *(uint2*)&Psl[w][li][(((2 * j + (lg >> 1)) ^ xh) * 8) + (lg & 1) * 4] = pw;
                }
                bf16x8 pb[2];
#pragma unroll
                for (int kk = 0; kk < 2; kk++)
                    pb[kk] = *(const bf16x8*)&Psl[w][li][((kk * 4 + lg) ^ xh) * 8];
                __builtin_amdgcn_s_setprio(1);
#pragma unroll
                for (int dd = 0; dd < 4; dd++)
#pragma unroll
                    for (int kk = 0; kk < 2; kk++)
                        oacc[q2][dd] = __builtin_amdgcn_mfma_f32_16x16x32_bf16(
                            av[dd][kk], pb[kk], oacc[q2][dd], 0, 0, 0);
                __builtin_amdgcn_s_setprio(0);
            }
        }

        // bias prefetch for next iteration (after pvv/av dead -> low reg peak)
        short4 bnxt[2][2][4];
        {
            int itn = (it + 1 < NIT) ? it + 1 : it;
#pragma unroll
            for (int q2 = 0; q2 < 2; q2++)
#pragma unroll
                for (int st = 0; st < 2; st++)
#pragma unroll
                    for (int j = 0; j < 4; j++)
                        bnxt[q2][st][j] =
                            *(const short4*)&browq[q2][(itn * 2 + st) * 64 + j * 16 + lg * 4];
        }

        wait_vm0_barrier();
#pragma unroll
        for (int q2 = 0; q2 < 2; q2++)
#pragma unroll
            for (int st = 0; st < 2; st++)
#pragma unroll
                for (int j = 0; j < 4; j++) bcur[q2][st][j] = bnxt[q2][st][j];
    }

    // epilogue: O[q][d] = O^T[d][q]/l ; cvt_pk + 8B stores, per q-group
#pragma unroll
    for (int q2 = 0; q2 < 2; q2++) {
        if (myq[q2] < NTOK) {
            float inv = 1.0f / lrun[q2];
            short* op = aout + ((size_t)b * NTOK + myq[q2]) * EMB + h * HD;
#pragma unroll
            for (int dd = 0; dd < 4; dd++) {
                uint2 o;
                o.x = pk2bf(oacc[q2][dd][0] * inv, oacc[q2][dd][1] * inv);
                o.y = pk2bf(oacc[q2][dd][2] * inv, oacc[q2][dd][3] * inv);
                *(uint2*)&op[dd * 16 + lg * 4] = o;
            }
        }
    }
}

// ---------------------------------------------------------------- launch
extern "C" void kernel_launch(void* const* d_in, const int* in_sizes, int n_in,
                              void* d_out, int out_size, void* d_ws, size_t ws_size,
                              hipStream_t stream) {
    (void)in_sizes; (void)n_in; (void)out_size; (void)ws_size;
    const float* x   = (const float*)d_in[0];
    const float* Wq  = (const float*)d_in[1];
    const float* bq  = (const float*)d_in[2];
    const float* Wk  = (const float*)d_in[3];
    const float* bk  = (const float*)d_in[4];
    const float* Wv  = (const float*)d_in[5];
    const float* bv  = (const float*)d_in[6];
    const float* Wp  = (const float*)d_in[7];
    const float* bp  = (const float*)d_in[8];
    const float* rel = (const float*)d_in[9];

    const size_t WN = (size_t)EMB * EMB;                    // 589824
    short* Wb   = (short*)d_ws;                             // [2304][768] bf16
    short* Wpb  = Wb + 3 * WN;                              // [768][768] bf16
    short* qnat = Wpb + WN;                                 // [MROWS][2304] bf16 (V third unused)
    short* xb   = qnat + (size_t)MROWS * QKVC;              // [MROWS][768] bf16
    short* aout = xb;                                       // ALIAS: xb dead after gemm0
    short* vtb  = xb + (size_t)MROWS * EMB;                 // [B][H][HD][640] bf16
    short* bexp = vtb + (size_t)BATCH * NHEAD * HD * NPAD;  // [H][640][640] bf16 (q-major, log2e-scaled)

    const int XN = MROWS * EMB;  // 14180352
    const int MT = (MROWS + 255) / 256;   // 73
    cast_f32_bf16<<<576, 256, 0, stream>>>(Wq, Wb, (int)WN);
    cast_f32_bf16<<<576, 256, 0, stream>>>(Wk, Wb + WN, (int)WN);
    cast_f32_bf16<<<576, 256, 0, stream>>>(Wv, Wb + 2 * WN, (int)WN);
    cast_f32_bf16<<<576, 256, 0, stream>>>(Wp, Wpb, (int)WN);
    cast_f32_bf16<<<13848, 256, 0, stream>>>(x, xb, XN);
    bias_expand<<<NPAD, NPAD, 0, stream>>>(rel, bexp);

    gemm_bt<0><<<9 * MT, 512, 0, stream>>>(xb, Wb, bq, bk, bv, qnat, vtb, MROWS);
    attn_kernel<<<BATCH * NHEAD * NQT, 256, 0, stream>>>(qnat, vtb, bexp, aout);
    gemm_bt<1><<<3 * MT, 512, 0, stream>>>(aout, Wpb, bp, bp, bp, d_out, nullptr, MROWS);
}

// Round 13
// 254.571 us; speedup vs baseline: 1.1769x; 1.1769x over previous
//
#include <hip/hip_runtime.h>
#include <hip/hip_bf16.h>
#include <stdint.h>

#define HGT   24
#define WID   24
#define NHEAD 12
#define EMB   768
#define HD    64
#define NGRID 576
#define NTOK  577
#define NPAD  640              // padded token dim (10 tiles of 64)
#define BATCH 32
#define MROWS (BATCH * NTOK)   // 18464
#define NKT   10
#define NIT   5                // 5 iterations x 128 keys
#define NQT   5                // 5 q-tiles of 128
#define QKVC  (3 * EMB)        // 2304

typedef __attribute__((ext_vector_type(8))) short bf16x8;
typedef __attribute__((ext_vector_type(4))) float f32x4;

__device__ __forceinline__ short f2bf(float f) {
    union { float f; unsigned u; } c; c.f = f;
    unsigned r = (c.u + 0x7FFFu + ((c.u >> 16) & 1u)) >> 16;
    return (short)(r & 0xFFFFu);
}
__device__ __forceinline__ float b2f(short s) {
    union { unsigned u; float f; } c; c.u = ((unsigned)(unsigned short)s) << 16;
    return c.f;
}
// packed f32x2 -> bf16x2 (compiler emits v_cvt_pk_bf16_f32)
__device__ __forceinline__ unsigned pk2bf(float a, float b) {
    __hip_bfloat162 h = __float22bfloat162_rn(make_float2(a, b));
    union { __hip_bfloat162 h; unsigned u; } c; c.h = h;
    return c.u;
}
__device__ __forceinline__ float fexp2(float x) {
#if __has_builtin(__builtin_amdgcn_exp2f)
    return __builtin_amdgcn_exp2f(x);
#else
    return __expf(x * 0.69314718f);
#endif
}

// async global->LDS, 16B per lane; LDS dest = wave-uniform base + lane*16
__device__ __forceinline__ void gload16(void* lds, const void* g) {
    __builtin_amdgcn_global_load_lds(
        (const __attribute__((address_space(1))) void*)g,
        (__attribute__((address_space(3))) void*)lds, 16, 0, 0);
}

__device__ __forceinline__ void wait_vm0_barrier() {
    asm volatile("s_waitcnt vmcnt(0)" ::: "memory");
    __builtin_amdgcn_s_barrier();
}

// bijective XCD-chunk swizzle (m204)
__device__ __forceinline__ int xcd_swizzle(int orig, int nwg) {
    int q = nwg >> 3, r = nwg & 7;
    int xcd = orig & 7, idx = orig >> 3;
    return (xcd < r) ? xcd * (q + 1) + idx : r * (q + 1) + (xcd - r) * q + idx;
}

// ---------------------------------------------------------------- fused cast f32->bf16 (x + 4 weights, one launch)
// exact partition: blocks [0,13848) -> x (13848*1024 = 14180352 elems)
//                  blocks [13848 + s*576, ...) s=0..3 -> Wq,Wk,Wv,Wp (576*1024 = 589824 each)
__global__ void cast_all(const float* __restrict__ x,
                         const float* __restrict__ Wq, const float* __restrict__ Wk,
                         const float* __restrict__ Wv, const float* __restrict__ Wp,
                         short* __restrict__ xb, short* __restrict__ Wb, short* __restrict__ Wpb) {
    const size_t WN = (size_t)EMB * EMB;
    int bid = blockIdx.x;
    const float* src;
    short* dst;
    int local;
    if (bid < 13848) {
        src = x; dst = xb; local = bid;
    } else {
        int s = (bid - 13848) / 576;
        local = (bid - 13848) - s * 576;
        if (s == 0)      { src = Wq; dst = Wb; }
        else if (s == 1) { src = Wk; dst = Wb + WN; }
        else if (s == 2) { src = Wv; dst = Wb + 2 * WN; }
        else             { src = Wp; dst = Wpb; }
    }
    int j = (local * 256 + threadIdx.x) * 4;
    float4 v = *(const float4*)(src + j);
    uint2 o;
    o.x = pk2bf(v.x, v.y);
    o.y = pk2bf(v.z, v.w);
    *(uint2*)(dst + j) = o;
}

// ---------------------------------------------------------------- bias table bf16 [H][q 640][k 640]
// PRE-SCALED by log2(e) (softmax runs in log2 domain).
__global__ void bias_expand(const float* __restrict__ rel, short* __restrict__ be) {
    const float L2E = 1.44269504f;
    int q = blockIdx.x;     // query 0..639
    int k = threadIdx.x;    // key   0..639
    float v[NHEAD];
    if (k >= NTOK) {
#pragma unroll
        for (int h = 0; h < NHEAD; h++) v[h] = -1e30f;
    } else if (q == 0 || q >= NTOK || k == 0) {
#pragma unroll
        for (int h = 0; h < NHEAD; h++) v[h] = 0.f;
    } else {
        int i = q - 1, j = k - 1;
        int idx = ((i / WID) - (j / WID) + HGT - 1) * (2 * WID - 1)
                + ((i % WID) - (j % WID) + WID - 1);
        const float* rp = rel + (size_t)idx * NHEAD;
#pragma unroll
        for (int h = 0; h < NHEAD; h++) v[h] = rp[h];
    }
#pragma unroll
    for (int h = 0; h < NHEAD; h++)
        be[((size_t)h * NPAD + q) * NPAD + k] = f2bf(v[h] * L2E);
}

// ---------------------------------------------------------------- GEMM  C = A @ B^T (+bias)
// 256x256 tile, BK=32, 8 waves (512 thr), 4 LDS buffers, uniform 3-step
// prefetch distance, counted vmcnt(8) (never 0 until tail), ONE barrier/step.
// Transposed accumulation (mfma(B,A)) -> wide C stores.
// MODE 0: NC=2304, bf16 out -> qnat[m][2304]; V third (cols>=1536) scatters
//         TRANSPOSED into vout[b][h][d][key(640)] (fuses transpose_v).
// MODE 1: NC=768, f32 out + b0.
template <int MODE>
__global__ __launch_bounds__(512) void gemm_bt(
    const short* __restrict__ A, const short* __restrict__ Bw,
    const float* __restrict__ b0, const float* __restrict__ b1, const float* __restrict__ b2,
    void* __restrict__ Outp, short* __restrict__ vout, int M)
{
    constexpr int NC  = (MODE == 0) ? QKVC : EMB;
    constexpr int NBX = NC / 256;     // 9 or 3
    constexpr int K   = EMB;          // 768
    constexpr int NST = K / 32;       // 24 K-steps

    __shared__ __align__(16) short Asl[4][256][32];   // 64 KB
    __shared__ __align__(16) short Bsl[4][256][32];   // 64 KB

    const int t    = threadIdx.x;
    const int lane = t & 63;
    const int w    = t >> 6;          // 0..7
    const int wm   = w >> 2;          // 0..1  (M half)
    const int wn   = w & 3;           // 0..3  (N quarter)
    const int lg   = lane >> 4;
    const int li   = lane & 15;

    const int nwg  = NBX * ((MROWS + 255) / 256);     // 9*73 or 3*73
    const int wgid = xcd_swizzle(blockIdx.x, nwg);
    const int tm   = (wgid / NBX) * 256;
    const int tn   = (wgid % NBX) * 256;

    const int drow = lane >> 2;                        // 0..15
    const int lc   = (lane & 3) ^ ((lane >> 3) & 3);   // source logical chunk
    const int xsw  = (li >> 1) & 3;                    // read-side chunk XOR

    const short* agp[2];
    const short* bgp[2];
#pragma unroll
    for (int gi = 0; gi < 2; gi++) {
        int rm = tm + gi * 128 + w * 16 + drow; if (rm >= M) rm = M - 1;
        agp[gi] = A  + (size_t)rm * K + lc * 8;
        bgp[gi] = Bw + (size_t)(tn + gi * 128 + w * 16 + drow) * K + lc * 8;
    }

    f32x4 acc[8][4];
#pragma unroll
    for (int i = 0; i < 8; i++)
#pragma unroll
        for (int j = 0; j < 4; j++) acc[i][j] = (f32x4){0.f, 0.f, 0.f, 0.f};

    // prologue: stage steps 0..2 (4 gloads/wave each)
#pragma unroll
    for (int ss = 0; ss < 3; ss++) {
        gload16(&Asl[ss][0 * 128 + w * 16][0], agp[0] + ss * 32);
        gload16(&Asl[ss][1 * 128 + w * 16][0], agp[1] + ss * 32);
        gload16(&Bsl[ss][0 * 128 + w * 16][0], bgp[0] + ss * 32);
        gload16(&Bsl[ss][1 * 128 + w * 16][0], bgp[1] + ss * 32);
    }

    for (int s = 0; s < NST; s++) {
        if (s < NST - 2)       asm volatile("s_waitcnt vmcnt(8)" ::: "memory");
        else if (s == NST - 2) asm volatile("s_waitcnt vmcnt(4)" ::: "memory");
        else                   asm volatile("s_waitcnt vmcnt(0)" ::: "memory");
        __builtin_amdgcn_s_barrier();

        const int cb = s & 3;
        bf16x8 af[8], bfv[4];
#pragma unroll
        for (int mi = 0; mi < 8; mi++)
            af[mi] = *(const bf16x8*)&Asl[cb][wm * 128 + mi * 16 + li][(lg ^ xsw) * 8];
#pragma unroll
        for (int nj = 0; nj < 4; nj++)
            bfv[nj] = *(const bf16x8*)&Bsl[cb][wn * 64 + nj * 16 + li][(lg ^ xsw) * 8];

        if (s + 3 < NST) {
            const int tb = (s + 3) & 3;
            const int ko = (s + 3) * 32;
            gload16(&Asl[tb][0 * 128 + w * 16][0], agp[0] + ko);
            gload16(&Asl[tb][1 * 128 + w * 16][0], agp[1] + ko);
            gload16(&Bsl[tb][0 * 128 + w * 16][0], bgp[0] + ko);
            gload16(&Bsl[tb][1 * 128 + w * 16][0], bgp[1] + ko);
        }

        __builtin_amdgcn_s_setprio(1);
#pragma unroll
        for (int mi = 0; mi < 8; mi++)
#pragma unroll
            for (int nj = 0; nj < 4; nj++)
                acc[mi][nj] = __builtin_amdgcn_mfma_f32_16x16x32_bf16(
                    bfv[nj], af[mi], acc[mi][nj], 0, 0, 0);   // transposed: C^T frags
        __builtin_amdgcn_s_setprio(0);
    }

    // epilogue: lane holds C[row = wm*128+mi*16+li][cols = ccb..ccb+3]
    if (MODE == 0 && tn >= 2 * EMB) {
        // V third: scatter transposed into vout[b][h][d][key]
#pragma unroll
        for (int nj = 0; nj < 4; nj++) {
            const int ccb = tn + wn * 64 + nj * 16 + lg * 4;
            const int e   = ccb - 2 * EMB;
            const int hh  = e >> 6, db = e & 63;
            const float4 bias4 = *(const float4*)&b2[e];
#pragma unroll
            for (int mi = 0; mi < 8; mi++) {
                int m = tm + wm * 128 + mi * 16 + li;
                if (m >= M) continue;
                int bi = m / NTOK;
                int n  = m - bi * NTOK;
                short* vr = vout + (((size_t)bi * NHEAD + hh) * HD + db) * NPAD + n;
                vr[0 * NPAD] = f2bf(acc[mi][nj][0] + bias4.x);
                vr[1 * NPAD] = f2bf(acc[mi][nj][1] + bias4.y);
                vr[2 * NPAD] = f2bf(acc[mi][nj][2] + bias4.z);
                vr[3 * NPAD] = f2bf(acc[mi][nj][3] + bias4.w);
            }
        }
    } else {
#pragma unroll
        for (int nj = 0; nj < 4; nj++) {
            const int ccb = tn + wn * 64 + nj * 16 + lg * 4;
            float4 bias4;
            if constexpr (MODE == 0) {
                int which = (ccb >= EMB) ? 1 : 0;   // V handled above
                const float* bb = (which == 0) ? b0 : b1;
                bias4 = *(const float4*)&bb[ccb - which * EMB];
            } else {
                bias4 = *(const float4*)&b0[ccb];
            }
#pragma unroll
            for (int mi = 0; mi < 8; mi++) {
                int m = tm + wm * 128 + mi * 16 + li;
                if (m >= M) continue;
                if constexpr (MODE == 0) {
                    uint2 o;
                    o.x = pk2bf(acc[mi][nj][0] + bias4.x, acc[mi][nj][1] + bias4.y);
                    o.y = pk2bf(acc[mi][nj][2] + bias4.z, acc[mi][nj][3] + bias4.w);
                    *(uint2*)&((short*)Outp)[(size_t)m * NC + ccb] = o;
                } else {
                    float4 o;
                    o.x = acc[mi][nj][0] + bias4.x;
                    o.y = acc[mi][nj][1] + bias4.y;
                    o.z = acc[mi][nj][2] + bias4.z;
                    o.w = acc[mi][nj][3] + bias4.w;
                    *(float4*)&((float*)Outp)[(size_t)m * NC + ccb] = o;
                }
            }
        }
    }
}

// ---------------------------------------------------------------- flash attention (swapped QK^T, log2 softmax)
// 512 threads (8 waves x 16 queries = 128 q per block); 2 KV tiles (128 keys)
// per iteration. [R11 version — best measured: 117.4 us]
__global__ __launch_bounds__(512) void attn_kernel(
    const short* __restrict__ qnat, const short* __restrict__ vt,
    const short* __restrict__ biasx, short* __restrict__ aout)
{
    __shared__ __align__(16) short Ksl[2][2][64][64];   // [buf][subtile][key][d]  32 KB
    __shared__ __align__(16) short Vsl[2][2][64][64];   // [buf][subtile][d][key]  32 KB
    __shared__ __align__(16) short Psl[8][16][64];      // [wave][q(li)][key]      16 KB

    const int wg = (blockIdx.x & 7) * (BATCH * NHEAD * NQT / 8) + (blockIdx.x >> 3);
    const int qt = wg % NQT;
    const int rest = wg / NQT;        // 0..383
    const int b  = rest & 31;
    const int h  = rest >> 5;

    const int t    = threadIdx.x;
    const int lane = t & 63;
    const int w    = t >> 6;          // 0..7
    const int lg   = lane >> 4;
    const int li   = lane & 15;
    const int xh   = li & 7;
    const int qbase = qt * 128;
    const int myq  = qbase + w * 16 + li;   // this lane's query column

    const float SCL = 0.18033688f;    // 0.125 * log2(e)

    const short* qp  = qnat + (size_t)b * NTOK * QKVC + h * HD;          // + n*QKVC
    const short* kp  = qp + EMB;
    const short* vtp = vt + ((size_t)b * NHEAD + h) * (size_t)HD * NPAD;
    const short* browq = biasx + ((size_t)h * NPAD + myq) * NPAD;        // [k] bf16 (log2-scaled)

    bf16x8 qf[2];   // B-fragment: Q[myq][k]
    {
        int qrow = myq < NTOK ? myq : NTOK - 1;
        qf[0] = *(const bf16x8*)(qp + (size_t)qrow * QKVC + lg * 8);
        qf[1] = *(const bf16x8*)(qp + (size_t)qrow * QKVC + 32 + lg * 8);
    }

    float mrun = -1e30f, lrun = 0.f;
    f32x4 oacc[4];
#pragma unroll
    for (int d = 0; d < 4; d++) oacc[d] = (f32x4){0.f, 0.f, 0.f, 0.f};

    const int srow = w * 8 + (lane >> 3);
    const int cofs = ((lane & 7) ^ (lane >> 3)) * 8;

    // prologue: stage iteration 0 (tiles 0,1)
#pragma unroll
    for (int st = 0; st < 2; st++) {
        int key = st * 64 + srow; if (key >= NTOK) key = NTOK - 1;
        gload16(&Ksl[0][st][w * 8][0], kp + (size_t)key * QKVC + cofs);
        gload16(&Vsl[0][st][w * 8][0], vtp + (size_t)srow * NPAD + st * 64 + cofs);
    }
    short4 bcur[2][4];
#pragma unroll
    for (int st = 0; st < 2; st++)
#pragma unroll
        for (int j = 0; j < 4; j++)
            bcur[st][j] = *(const short4*)&browq[st * 64 + j * 16 + lg * 4];
    wait_vm0_barrier();

    for (int it = 0; it < NIT; it++) {
        const int cb = it & 1, nb = cb ^ 1;

        // prefetch next iteration's K/V (LDS) and bias (regs)
        if (it + 1 < NIT) {
#pragma unroll
            for (int st = 0; st < 2; st++) {
                int key = (it + 1) * 128 + st * 64 + srow; if (key >= NTOK) key = NTOK - 1;
                gload16(&Ksl[nb][st][w * 8][0], kp + (size_t)key * QKVC + cofs);
                gload16(&Vsl[nb][st][w * 8][0],
                        vtp + (size_t)srow * NPAD + (it + 1) * 128 + st * 64 + cofs);
            }
        }
        short4 bnxt[2][4];
        {
            int itn = (it + 1 < NIT) ? it + 1 : it;
#pragma unroll
            for (int st = 0; st < 2; st++)
#pragma unroll
                for (int j = 0; j < 4; j++)
                    bnxt[st][j] = *(const short4*)&browq[(itn * 2 + st) * 64 + j * 16 + lg * 4];
        }

        // S^T = K @ Q^T (log2 domain) + bias^T, both sub-tiles (16 MFMA cluster)
        float pvv[2][4][4];
        __builtin_amdgcn_s_setprio(1);
#pragma unroll
        for (int st = 0; st < 2; st++) {
#pragma unroll
            for (int j = 0; j < 4; j++) {
                bf16x8 ak0 = *(const bf16x8*)&Ksl[cb][st][j * 16 + li][(lg ^ xh) * 8];
                bf16x8 ak1 = *(const bf16x8*)&Ksl[cb][st][j * 16 + li][((4 + lg) ^ xh) * 8];
                f32x4 s = (f32x4){0.f, 0.f, 0.f, 0.f};
                s = __builtin_amdgcn_mfma_f32_16x16x32_bf16(ak0, qf[0], s, 0, 0, 0);
                s = __builtin_amdgcn_mfma_f32_16x16x32_bf16(ak1, qf[1], s, 0, 0, 0);
                pvv[st][j][0] = fmaf(s[0], SCL, b2f(bcur[st][j].x));
                pvv[st][j][1] = fmaf(s[1], SCL, b2f(bcur[st][j].y));
                pvv[st][j][2] = fmaf(s[2], SCL, b2f(bcur[st][j].z));
                pvv[st][j][3] = fmaf(s[3], SCL, b2f(bcur[st][j].w));
            }
        }
        __builtin_amdgcn_s_setprio(0);

        // online softmax over 128 keys (log2 domain), defer-max (T13)
        float mt = pvv[0][0][0];
#pragma unroll
        for (int st = 0; st < 2; st++)
#pragma unroll
            for (int j = 0; j < 4; j++)
#pragma unroll
                for (int r = 0; r < 4; r++) mt = fmaxf(mt, pvv[st][j][r]);
        mt = fmaxf(mt, __shfl_xor(mt, 16, 64));
        mt = fmaxf(mt, __shfl_xor(mt, 32, 64));
        if (__any(mt > mrun + 8.0f)) {
            float nm  = fmaxf(mrun, mt);
            float fac = fexp2(mrun - nm);
            mrun = nm;
            lrun *= fac;
#pragma unroll
            for (int d = 0; d < 4; d++) oacc[d] *= fac;
        }
        float rs = 0.f;
#pragma unroll
        for (int st = 0; st < 2; st++)
#pragma unroll
            for (int j = 0; j < 4; j++)
#pragma unroll
                for (int r = 0; r < 4; r++) {
                    float p = fexp2(pvv[st][j][r] - mrun);
                    pvv[st][j][r] = p;
                    rs += p;
                }
        rs += __shfl_xor(rs, 16, 64);
        rs += __shfl_xor(rs, 32, 64);
        lrun += rs;

        // PV per sub-tile (Psl reused; wave-private, lgkm-ordered)
#pragma unroll
        for (int st = 0; st < 2; st++) {
#pragma unroll
            for (int j = 0; j < 4; j++) {
                uint2 pw;
                pw.x = pk2bf(pvv[st][j][0], pvv[st][j][1]);
                pw.y = pk2bf(pvv[st][j][2], pvv[st][j][3]);
                *(uint2*)&Psl[w][li][(((2 * j + (lg >> 1)) ^ xh) * 8) + (lg & 1) * 4] = pw;
            }
            __builtin_amdgcn_s_setprio(1);
#pragma unroll
            for (int dd = 0; dd < 4; dd++) {
#pragma unroll
                for (int kk = 0; kk < 2; kk++) {
                    bf16x8 av = *(const bf16x8*)&Vsl[cb][st][dd * 16 + li][((kk * 4 + lg) ^ xh) * 8];
                    bf16x8 pb = *(const bf16x8*)&Psl[w][li][((kk * 4 + lg) ^ xh) * 8];
                    oacc[dd] = __builtin_amdgcn_mfma_f32_16x16x32_bf16(av, pb, oacc[dd], 0, 0, 0);
                }
            }
            __builtin_amdgcn_s_setprio(0);
        }

        wait_vm0_barrier();
#pragma unroll
        for (int st = 0; st < 2; st++)
#pragma unroll
            for (int j = 0; j < 4; j++) bcur[st][j] = bnxt[st][j];
    }

    // epilogue: O[q][d] = O^T[d][q]/l ; cvt_pk + 8B stores
    if (myq < NTOK) {
        float inv = 1.0f / lrun;
        short* op = aout + ((size_t)b * NTOK + myq) * EMB + h * HD;
#pragma unroll
        for (int dd = 0; dd < 4; dd++) {
            uint2 o;
            o.x = pk2bf(oacc[dd][0] * inv, oacc[dd][1] * inv);
            o.y = pk2bf(oacc[dd][2] * inv, oacc[dd][3] * inv);
            *(uint2*)&op[dd * 16 + lg * 4] = o;
        }
    }
}

// ---------------------------------------------------------------- launch
extern "C" void kernel_launch(void* const* d_in, const int* in_sizes, int n_in,
                              void* d_out, int out_size, void* d_ws, size_t ws_size,
                              hipStream_t stream) {
    (void)in_sizes; (void)n_in; (void)out_size; (void)ws_size;
    const float* x   = (const float*)d_in[0];
    const float* Wq  = (const float*)d_in[1];
    const float* bq  = (const float*)d_in[2];
    const float* Wk  = (const float*)d_in[3];
    const float* bk  = (const float*)d_in[4];
    const float* Wv  = (const float*)d_in[5];
    const float* bv  = (const float*)d_in[6];
    const float* Wp  = (const float*)d_in[7];
    const float* bp  = (const float*)d_in[8];
    const float* rel = (const float*)d_in[9];

    const size_t WN = (size_t)EMB * EMB;                    // 589824
    short* Wb   = (short*)d_ws;                             // [2304][768] bf16
    short* Wpb  = Wb + 3 * WN;                              // [768][768] bf16
    short* qnat = Wpb + WN;                                 // [MROWS][2304] bf16 (V third unused)
    short* xb   = qnat + (size_t)MROWS * QKVC;              // [MROWS][768] bf16
    short* aout = xb;                                       // ALIAS: xb dead after gemm0
    short* vtb  = xb + (size_t)MROWS * EMB;                 // [B][H][HD][640] bf16
    short* bexp = vtb + (size_t)BATCH * NHEAD * HD * NPAD;  // [H][640][640] bf16 (q-major, log2e-scaled)

    const int MT = (MROWS + 255) / 256;   // 73
    cast_all<<<13848 + 4 * 576, 256, 0, stream>>>(x, Wq, Wk, Wv, Wp, xb, Wb, Wpb);
    bias_expand<<<NPAD, NPAD, 0, stream>>>(rel, bexp);

    gemm_bt<0><<<9 * MT, 512, 0, stream>>>(xb, Wb, bq, bk, bv, qnat, vtb, MROWS);
    attn_kernel<<<BATCH * NHEAD * NQT, 512, 0, stream>>>(qnat, vtb, bexp, aout);
    gemm_bt<1><<<3 * MT, 512, 0, stream>>>(aout, Wpb, bp, bp, bp, d_out, nullptr, MROWS);
}